// Round 9
// baseline (430.574 us; speedup 1.0000x reference)
//
#include <hip/hip_runtime.h>
#include <math.h>

#define NROWS 8192
#define DIM   1024
#define KDIM  1024           // GEMM K dimension (pure-bf16 hi)
#define KSEL  5
#define TOPK  6
#define QB    128            // queries per block
#define KBB   128            // keys per block
#define NKB   (NROWS / KBB)  // key blocks = 64 (also lists per row)
#define NQB   (NROWS / QB)   // query blocks = 64
#define NT    (KDIM / 64)    // K-steps = 16
#define MPS   49             // gemm mbuf per-query stride in float2 (48->49)

typedef __attribute__((ext_vector_type(8))) short bf16x8;
typedef __attribute__((ext_vector_type(4))) float f32x4;

// ---------------------------------------------------------------------------
// ws layout:
//   [0]   : int match counter   [4] : int done counter (memset 8 B)
//   [256] : Q2 bf16[8192][1024] (row-XOR-preswizzled)  16 MB
//   [+16M]: K2 bf16[8192][1024] (row-XOR-preswizzled)  16 MB
//   [+32M]: partials float2[8192][64][6]               25.2 MB
//
// Round-24 = Round-23 with the block-merge indexing FIXED.
//   r23 failed correctness (absmax 2.2e-4): slot=wkh dropped l4, so the 4
//   l4-threads (which hold DISJOINT key sub-lists: kk = ...+l4*4+reg)
//   clobbered one mbuf slot — only a race-survivor's 32-key subset got
//   merged. Fix: slot = wkh*4+l4 (8 slots/query, as r22 had). To keep
//   LDS <= 25 KB (4 blocks/CU), merge 64 queries per pass, 2 passes.
//
// Round-23 rationale (unchanged, now actually measured):
//   r22's zero-LDS/zero-barrier loop == LDS variants (260 vs 237-257):
//   staging machinery exonerated. Invariants: 2 waves/SIMD (128-AGPR acc),
//   FETCH ~3x inputs, ~440 GB/s demand vs 1.6 TB/s proven headroom, no
//   pipe >50% => miss-latency-bound at 2 waves/SIMD.
//   Fix A: 128x128 tile / 4 waves / acc[4][4]=64 AGPR, launch_bounds(256,4).
//   Fix B: bijective XCD chunking (4096 blocks, 512/XCD, kb-major).
//   Sentinels: absmax 0, VGPR<=128, WRITE ~26 MB.
//   Predict: Occupancy ~40%, FETCH 40-60 MB, gemm 120-160 us.
// ---------------------------------------------------------------------------

__device__ __forceinline__ unsigned short f2bf(float x) {
    unsigned u = __float_as_uint(x);
    unsigned r = (u + 0x7fffu + ((u >> 16) & 1u)) >> 16;   // RNE
    return (unsigned short)r;
}

// full tie-break compare (merge paths — arbitrary id order there)
__device__ __forceinline__ bool better(float v, int id, float v2, int id2) {
    return (v > v2) || (v == v2 && id < id2);
}
__device__ __forceinline__ void insert6(float v, int id, float* tv, int* ti) {
    if (!better(v, id, tv[TOPK - 1], ti[TOPK - 1])) return;
    int j = TOPK - 1;
    while (j > 0 && better(v, id, tv[j - 1], ti[j - 1])) {
        tv[j] = tv[j - 1]; ti[j] = ti[j - 1]; --j;
    }
    tv[j] = v; ti[j] = id;
}

// branchless strict insert (ascending-id stream => strict '>' is exact).
__device__ __forceinline__ void ins6(float v, int id, float* tv, int* ti) {
    if (v <= tv[5]) return;
    bool gt[6];
#pragma unroll
    for (int j = 0; j < 6; ++j) gt[j] = v > tv[j];
#pragma unroll
    for (int j = 5; j >= 1; --j)
        if (gt[j - 1]) { tv[j] = tv[j - 1]; ti[j] = ti[j - 1]; }
    if (gt[0]) { tv[0] = v; ti[0] = id; }
#pragma unroll
    for (int j = 1; j < 6; ++j)
        if (gt[j] && !gt[j - 1]) { tv[j] = v; ti[j] = id; }
}

// --- 1) normalize -> bf16 (hi only), wave-per-row, no block sync ------------
// Layout: chunk t (0..127) = elems {4t..4t+3, 512+4t..512+4t+3} stored as
// 8-group at (t>>3)*64 + ((t&7)^(r&7))*8.  (validated absmax=0, r6/r7)
__global__ __launch_bounds__(256) void prep_kernel(
        const float* __restrict__ q, const float* __restrict__ kb,
        unsigned short* __restrict__ Q2, unsigned short* __restrict__ K2) {
    const int w = threadIdx.x >> 6, lane = threadIdx.x & 63;
    const int b = blockIdx.x * 4 + w;    // row 0..16383
    const bool isQ = (b < NROWS);
    const int r = isQ ? b : b - NROWS;
    const float* src = (isQ ? q : kb) + (size_t)r * DIM;
    unsigned short* D = (isQ ? Q2 : K2) + (size_t)r * KDIM;

    float4 v[4];
#pragma unroll
    for (int i = 0; i < 4; ++i)
        v[i] = *(const float4*)(src + i * 256 + lane * 4);   // coalesced

    float s = 0.f;
#pragma unroll
    for (int i = 0; i < 4; ++i)
        s += v[i].x * v[i].x + v[i].y * v[i].y + v[i].z * v[i].z + v[i].w * v[i].w;
    for (int o = 32; o; o >>= 1) s += __shfl_down(s, o, 64);
    s = __shfl(s, 0, 64);                 // broadcast row sum
    const float inv = 1.0f / fmaxf(sqrtf(s), 1e-12f);

    bf16x8 g0, g1;
    g0[0] = (short)f2bf(v[0].x * inv); g0[1] = (short)f2bf(v[0].y * inv);
    g0[2] = (short)f2bf(v[0].z * inv); g0[3] = (short)f2bf(v[0].w * inv);
    g0[4] = (short)f2bf(v[2].x * inv); g0[5] = (short)f2bf(v[2].y * inv);
    g0[6] = (short)f2bf(v[2].z * inv); g0[7] = (short)f2bf(v[2].w * inv);
    g1[0] = (short)f2bf(v[1].x * inv); g1[1] = (short)f2bf(v[1].y * inv);
    g1[2] = (short)f2bf(v[1].z * inv); g1[3] = (short)f2bf(v[1].w * inv);
    g1[4] = (short)f2bf(v[3].x * inv); g1[5] = (short)f2bf(v[3].y * inv);
    g1[6] = (short)f2bf(v[3].z * inv); g1[7] = (short)f2bf(v[3].w * inv);

    const int perm = ((lane & 7) ^ (r & 7)) * 8;
    const int off0 = (lane >> 3) * 64 + perm;            // chunk l
    const int off1 = (8 + (lane >> 3)) * 64 + perm;      // chunk l+64
    *(bf16x8*)(D + off0) = g0;
    *(bf16x8*)(D + off1) = g1;
}

// --- 2) 128x128 GEMM, direct global->reg, 4 waves, 64-AGPR acc --------------
__global__ __launch_bounds__(256, 4) void gemm_topk_kernel(
        const unsigned short* __restrict__ Q2, const unsigned short* __restrict__ K2,
        float2* __restrict__ partials) {
    __shared__ float2 mbuf[64 * MPS];    // merge buffer only (25 KB)

    // ---- bijective XCD-chunked swizzle: 8 consecutive kb per XCD ----------
    const int bid = blockIdx.y * NQB + blockIdx.x;       // 0..4095
    const int vb  = (bid & 7) * (NQB * NKB / 8) + (bid >> 3);
    const int kbi = vb >> 6;             // 0..63 (8 consecutive per XCD)
    const int qbi = vb & 63;             // 0..63
    const int qbase = qbi * QB;
    const int kbase = kbi * KBB;

    const int tid = threadIdx.x;         // 0..255 (4 waves)
    const int w = tid >> 6, l = tid & 63;
    const int l15 = l & 15, l4 = l >> 4;
    const int wkh = w & 1;               // key half   (64 keys)
    const int wqh = w >> 1;              // query half (64 queries)
    const int xr = l15 & 7;

    // fragment global element offsets (fit 32-bit: max 8192*1024)
    const unsigned kof = (unsigned)(kbase + wkh * 64 + l15) * KDIM;
    unsigned qof[4];
#pragma unroll
    for (int nt = 0; nt < 4; ++nt)
        qof[nt] = (unsigned)(qbase + wqh * 64 + nt * 16 + l15) * KDIM;
    const unsigned pe0 = (unsigned)((l4 ^ xr) * 8);
    const unsigned pe1 = (unsigned)(((4 + l4) ^ xr) * 8);

    f32x4 acc[4][4];   // [mt = key-tile][nt = query-tile]  (64 AGPR)
#pragma unroll
    for (int mt = 0; mt < 4; ++mt)
#pragma unroll
        for (int nt = 0; nt < 4; ++nt) acc[mt][nt] = (f32x4){0.f, 0.f, 0.f, 0.f};

#pragma unroll 1
    for (int t = 0; t < NT; ++t) {
        const unsigned tb = (unsigned)t * 64u;
#pragma unroll
        for (int ks = 0; ks < 2; ++ks) {
            const unsigned pk = tb + (ks ? pe1 : pe0);
            bf16x8 bq[4];
#pragma unroll
            for (int nt = 0; nt < 4; ++nt)
                bq[nt] = *(const bf16x8*)(Q2 + qof[nt] + pk);
            bf16x8 af[4];
#pragma unroll
            for (int mt = 0; mt < 4; ++mt)
                af[mt] = *(const bf16x8*)(K2 + kof + (unsigned)mt * (16u * KDIM) + pk);
            __builtin_amdgcn_s_setprio(1);
#pragma unroll
            for (int mt = 0; mt < 4; ++mt)
#pragma unroll
                for (int nt = 0; nt < 4; ++nt)
                    acc[mt][nt] = __builtin_amdgcn_mfma_f32_16x16x32_bf16(
                        af[mt], bq[nt], acc[mt][nt], 0, 0, 0);
            __builtin_amdgcn_s_setprio(0);
        }
    }

    // ---- in-register top-6: 16 keys/thread per nt-list --------------------
    float tvl[4][6]; int til[4][6];
#pragma unroll
    for (int n = 0; n < 4; ++n)
#pragma unroll
        for (int i = 0; i < 6; ++i) { tvl[n][i] = -INFINITY; til[n][i] = 0x7fffffff; }

#pragma unroll
    for (int nt = 0; nt < 4; ++nt) {
#pragma unroll
        for (int mt = 0; mt < 4; ++mt) {
            const f32x4 a = acc[mt][nt];
            const float m4 = fmaxf(fmaxf(a.x, a.y), fmaxf(a.z, a.w));
            if (m4 > tvl[nt][5]) {
                const int kk = kbase + wkh * 64 + mt * 16 + l4 * 4;
                ins6(a.x, kk + 0, tvl[nt], til[nt]);
                ins6(a.y, kk + 1, tvl[nt], til[nt]);
                ins6(a.z, kk + 2, tvl[nt], til[nt]);
                ins6(a.w, kk + 3, tvl[nt], til[nt]);
            }
        }
    }

    // ---- block merge: 8 slots/query (wkh,l4), 64 queries per pass ---------
    const int slot = wkh * 4 + l4;       // 0..7  (l4 lists are DISJOINT keys!)
#pragma unroll 1
    for (int h = 0; h < 2; ++h) {
        if (wqh == h) {                  // waves owning queries h*64..h*64+63
#pragma unroll
            for (int nt = 0; nt < 4; ++nt) {
                const int ql = nt * 16 + l15;            // 0..63
                float2* dst = mbuf + (size_t)ql * MPS + slot * 6;
#pragma unroll
                for (int e = 0; e < 6; ++e)
                    dst[e] = make_float2(tvl[nt][e], __int_as_float(til[nt][e]));
            }
        }
        __syncthreads();
        if (tid < 64) {                  // one thread per query merges 8 lists
            float tv[6]; int ti[6];
#pragma unroll
            for (int i = 0; i < 6; ++i) { tv[i] = -INFINITY; ti[i] = 0x7fffffff; }
            const float2* src = mbuf + (size_t)tid * MPS;
            for (int e = 0; e < 48; ++e) {
                float2 p = src[e];
                if (p.x < tv[5]) continue;
                insert6(p.x, __float_as_int(p.y), tv, ti);
            }
            size_t off = ((size_t)(qbase + h * 64 + tid) * NKB + kbi) * TOPK;
#pragma unroll
            for (int i = 0; i < 6; ++i)
                partials[off + i] = make_float2(tv[i], __int_as_float(ti[i]));
        }
        __syncthreads();
    }
}

// --- 3) parallel merge + fused finalize (device-scope handoff) --------------
__global__ __launch_bounds__(256) void merge_kernel(
        const float2* __restrict__ partials,
        const int* __restrict__ query_ids, const int* __restrict__ key_ids,
        int* __restrict__ counter, int* __restrict__ done,
        float* __restrict__ out) {
    __shared__ float2 lbuf[32][49];      // [row-in-block][8 parts * 6, pad 49]
    __shared__ int sc[32];
    const int tid  = threadIdx.x;
    const int rloc = tid >> 3;           // 0..31
    const int part = tid & 7;            // 0..7
    const int row  = blockIdx.x * 32 + rloc;

    // stage 1: each thread merges 8 of the 64 lists (48 entries, coalesced)
    float tv[6]; int ti[6];
#pragma unroll
    for (int i = 0; i < 6; ++i) { tv[i] = -INFINITY; ti[i] = 0x7fffffff; }
    const float2* src = partials + ((size_t)row * NKB + part * 8) * TOPK;
#pragma unroll
    for (int e = 0; e < 48; ++e) {
        float2 p = src[e];
        if (p.x < tv[5]) continue;
        insert6(p.x, __float_as_int(p.y), tv, ti);
    }
#pragma unroll
    for (int i = 0; i < 6; ++i)
        lbuf[rloc][part * 6 + i] = make_float2(tv[i], __int_as_float(ti[i]));
    __syncthreads();

    // stage 2: one thread per row merges the 8 partial lists + counts
    if (part == 0) {
        float tv2[6]; int ti2[6];
#pragma unroll
        for (int i = 0; i < 6; ++i) { tv2[i] = -INFINITY; ti2[i] = 0x7fffffff; }
#pragma unroll
        for (int e = 0; e < 48; ++e) {
            float2 p = lbuf[rloc][e];
            if (p.x < tv2[5]) continue;
            insert6(p.x, __float_as_int(p.y), tv2, ti2);
        }
        const int qid = query_ids[row];
        int cnt = 0;
#pragma unroll
        for (int r = 1; r < TOPK; ++r)
            cnt += (key_ids[ti2[r]] == qid) ? 1 : 0;
        sc[rloc] = cnt;
    }
    __syncthreads();
    if (tid == 0) {
        int c = 0;
#pragma unroll
        for (int i = 0; i < 32; ++i) c += sc[i];
        atomicAdd(counter, c);
        __threadfence();                 // counter-add visible before done-add
        int prev = atomicAdd(done, 1);
        if (prev == gridDim.x - 1) {     // last block finalizes
            int total = atomicAdd(counter, 0);   // coherent read
            out[0] = (float)total / (float)(NROWS * KSEL);
        }
    }
}

extern "C" void kernel_launch(void* const* d_in, const int* in_sizes, int n_in,
                              void* d_out, int out_size, void* d_ws, size_t ws_size,
                              hipStream_t stream) {
    (void)in_sizes; (void)n_in; (void)out_size; (void)ws_size;
    const int*   query_ids = (const int*)d_in[0];
    const int*   key_ids   = (const int*)d_in[1];
    const float* q         = (const float*)d_in[2];
    const float* kb        = (const float*)d_in[3];

    char* ws = (char*)d_ws;
    const size_t MB16 = (size_t)NROWS * KDIM * sizeof(unsigned short);  // 16 MB
    int*            counter  = (int*)ws;          // [0]=matches, [1]=done
    unsigned short* Q2       = (unsigned short*)(ws + 256);
    unsigned short* K2       = (unsigned short*)(ws + 256 + MB16);
    float2*         partials = (float2*)(ws + 256 + 2 * MB16);

    hipMemsetAsync(counter, 0, 2 * sizeof(int), stream);
    prep_kernel<<<(2 * NROWS) / 4, 256, 0, stream>>>(q, kb, Q2, K2);
    gemm_topk_kernel<<<dim3(NQB, NKB), 256, 0, stream>>>(Q2, K2, partials);
    merge_kernel<<<NROWS / 32, 256, 0, stream>>>(partials, query_ids, key_ids,
                                                 counter, counter + 1,
                                                 (float*)d_out);
}

// Round 10
// 393.725 us; speedup vs baseline: 1.0936x; 1.0936x over previous
//
#include <hip/hip_runtime.h>
#include <math.h>

#define NROWS 8192
#define DIM   1024
#define KDIM  1024           // GEMM K dimension (pure-bf16 hi)
#define KSEL  5
#define TOPK  6
#define QB    128            // queries per block
#define KBB   128            // keys per block
#define NKB   (NROWS / KBB)  // key blocks = 64 (also lists per row)
#define NQB   (NROWS / QB)   // query blocks = 64
#define NT    (KDIM / 64)    // K-steps = 16
#define MPS   49             // gemm mbuf per-query stride in float2 (48->49)

typedef __attribute__((ext_vector_type(8))) short bf16x8;
typedef __attribute__((ext_vector_type(4))) float f32x4;

// ---------------------------------------------------------------------------
// ws layout:
//   [0]   : int match counter   [4] : int done counter (memset 8 B)
//   [256] : Q2 bf16[8192][1024] (row-XOR-preswizzled)  16 MB
//   [+16M]: K2 bf16[8192][1024] (row-XOR-preswizzled)  16 MB
//   [+32M]: partials float2[8192][64][6]               25.2 MB
//
// Round-25: qb-major XCD swizzle (single change vs r24).
//   r24 verdict: occupancy fix WORKED (19->42%, memory rate 480 GB/s ->
//   1.85 TB/s, exactly the predicted concurrency unlock) but FETCH went
//   98->534 MB: kb-major intra-XCD order made the ~128 concurrent blocks
//   per XCD span all 64 Q-panels -> 16 MB Q streamed through 4 MB L2
//   repeatedly. dur == (FETCH+WRITE)/rate again => now TRAFFIC-bound.
//   Fix: qb-major within the XCD's 8-kbi chunk:
//     kbi = (bid&7)*8 + ((bid>>3)&7), qbi = bid>>6   (bit-perm, bijective)
//   Concurrent window/XCD = ~16 qbi x 8 kbi: K-chunk (2 MB) L2-pinned all
//   run; each Q-panel read by its 8 kl-blocks while resident, then done.
//   Beyond-L2 demand ~ 8x16MB Q + 16MB K + 25MB partials ~ 175 MB.
//   Predict: FETCH 534 -> 150-220 MB; gemm 314 -> 110-170 us (if rate
//   binding); MfmaUtil -> 30-40; occupancy/VGPR/WRITE flat.
//   Attribution: FETCH down + dur flat -> latency again (next: K-unroll
//   prefetch). FETCH flat -> bid%8!=XCD assumption wrong.
// ---------------------------------------------------------------------------

__device__ __forceinline__ unsigned short f2bf(float x) {
    unsigned u = __float_as_uint(x);
    unsigned r = (u + 0x7fffu + ((u >> 16) & 1u)) >> 16;   // RNE
    return (unsigned short)r;
}

// full tie-break compare (merge paths — arbitrary id order there)
__device__ __forceinline__ bool better(float v, int id, float v2, int id2) {
    return (v > v2) || (v == v2 && id < id2);
}
__device__ __forceinline__ void insert6(float v, int id, float* tv, int* ti) {
    if (!better(v, id, tv[TOPK - 1], ti[TOPK - 1])) return;
    int j = TOPK - 1;
    while (j > 0 && better(v, id, tv[j - 1], ti[j - 1])) {
        tv[j] = tv[j - 1]; ti[j] = ti[j - 1]; --j;
    }
    tv[j] = v; ti[j] = id;
}

// branchless strict insert (ascending-id stream => strict '>' is exact).
__device__ __forceinline__ void ins6(float v, int id, float* tv, int* ti) {
    if (v <= tv[5]) return;
    bool gt[6];
#pragma unroll
    for (int j = 0; j < 6; ++j) gt[j] = v > tv[j];
#pragma unroll
    for (int j = 5; j >= 1; --j)
        if (gt[j - 1]) { tv[j] = tv[j - 1]; ti[j] = ti[j - 1]; }
    if (gt[0]) { tv[0] = v; ti[0] = id; }
#pragma unroll
    for (int j = 1; j < 6; ++j)
        if (gt[j] && !gt[j - 1]) { tv[j] = v; ti[j] = id; }
}

// --- 1) normalize -> bf16 (hi only), wave-per-row, no block sync ------------
// Layout: chunk t (0..127) = elems {4t..4t+3, 512+4t..512+4t+3} stored as
// 8-group at (t>>3)*64 + ((t&7)^(r&7))*8.  (validated absmax=0, r6/r7/r9)
__global__ __launch_bounds__(256) void prep_kernel(
        const float* __restrict__ q, const float* __restrict__ kb,
        unsigned short* __restrict__ Q2, unsigned short* __restrict__ K2) {
    const int w = threadIdx.x >> 6, lane = threadIdx.x & 63;
    const int b = blockIdx.x * 4 + w;    // row 0..16383
    const bool isQ = (b < NROWS);
    const int r = isQ ? b : b - NROWS;
    const float* src = (isQ ? q : kb) + (size_t)r * DIM;
    unsigned short* D = (isQ ? Q2 : K2) + (size_t)r * KDIM;

    float4 v[4];
#pragma unroll
    for (int i = 0; i < 4; ++i)
        v[i] = *(const float4*)(src + i * 256 + lane * 4);   // coalesced

    float s = 0.f;
#pragma unroll
    for (int i = 0; i < 4; ++i)
        s += v[i].x * v[i].x + v[i].y * v[i].y + v[i].z * v[i].z + v[i].w * v[i].w;
    for (int o = 32; o; o >>= 1) s += __shfl_down(s, o, 64);
    s = __shfl(s, 0, 64);                 // broadcast row sum
    const float inv = 1.0f / fmaxf(sqrtf(s), 1e-12f);

    bf16x8 g0, g1;
    g0[0] = (short)f2bf(v[0].x * inv); g0[1] = (short)f2bf(v[0].y * inv);
    g0[2] = (short)f2bf(v[0].z * inv); g0[3] = (short)f2bf(v[0].w * inv);
    g0[4] = (short)f2bf(v[2].x * inv); g0[5] = (short)f2bf(v[2].y * inv);
    g0[6] = (short)f2bf(v[2].z * inv); g0[7] = (short)f2bf(v[2].w * inv);
    g1[0] = (short)f2bf(v[1].x * inv); g1[1] = (short)f2bf(v[1].y * inv);
    g1[2] = (short)f2bf(v[1].z * inv); g1[3] = (short)f2bf(v[1].w * inv);
    g1[4] = (short)f2bf(v[3].x * inv); g1[5] = (short)f2bf(v[3].y * inv);
    g1[6] = (short)f2bf(v[3].z * inv); g1[7] = (short)f2bf(v[3].w * inv);

    const int perm = ((lane & 7) ^ (r & 7)) * 8;
    const int off0 = (lane >> 3) * 64 + perm;            // chunk l
    const int off1 = (8 + (lane >> 3)) * 64 + perm;      // chunk l+64
    *(bf16x8*)(D + off0) = g0;
    *(bf16x8*)(D + off1) = g1;
}

// --- 2) 128x128 GEMM, direct global->reg, 4 waves, 64-AGPR acc --------------
__global__ __launch_bounds__(256, 4) void gemm_topk_kernel(
        const unsigned short* __restrict__ Q2, const unsigned short* __restrict__ K2,
        float2* __restrict__ partials) {
    __shared__ float2 mbuf[64 * MPS];    // merge buffer only (25 KB)

    // ---- qb-major XCD swizzle (bit-permutation of bid; bijective) ---------
    //   XCD x (= bid&7 under HW round-robin) owns kbi in [8x, 8x+8):
    //   its 2 MB K-chunk stays L2-resident; concurrent window covers ~16
    //   consecutive qbi so each Q-panel is read 8x while L2-hot, once.
    const int bid = blockIdx.y * NQB + blockIdx.x;       // 0..4095
    const int kbi = (bid & 7) * 8 + ((bid >> 3) & 7);    // 0..63
    const int qbi = bid >> 6;                            // 0..63
    const int qbase = qbi * QB;
    const int kbase = kbi * KBB;

    const int tid = threadIdx.x;         // 0..255 (4 waves)
    const int w = tid >> 6, l = tid & 63;
    const int l15 = l & 15, l4 = l >> 4;
    const int wkh = w & 1;               // key half   (64 keys)
    const int wqh = w >> 1;              // query half (64 queries)
    const int xr = l15 & 7;

    // fragment global element offsets (fit 32-bit: max 8192*1024)
    const unsigned kof = (unsigned)(kbase + wkh * 64 + l15) * KDIM;
    unsigned qof[4];
#pragma unroll
    for (int nt = 0; nt < 4; ++nt)
        qof[nt] = (unsigned)(qbase + wqh * 64 + nt * 16 + l15) * KDIM;
    const unsigned pe0 = (unsigned)((l4 ^ xr) * 8);
    const unsigned pe1 = (unsigned)(((4 + l4) ^ xr) * 8);

    f32x4 acc[4][4];   // [mt = key-tile][nt = query-tile]  (64 AGPR)
#pragma unroll
    for (int mt = 0; mt < 4; ++mt)
#pragma unroll
        for (int nt = 0; nt < 4; ++nt) acc[mt][nt] = (f32x4){0.f, 0.f, 0.f, 0.f};

#pragma unroll 1
    for (int t = 0; t < NT; ++t) {
        const unsigned tb = (unsigned)t * 64u;
#pragma unroll
        for (int ks = 0; ks < 2; ++ks) {
            const unsigned pk = tb + (ks ? pe1 : pe0);
            bf16x8 bq[4];
#pragma unroll
            for (int nt = 0; nt < 4; ++nt)
                bq[nt] = *(const bf16x8*)(Q2 + qof[nt] + pk);
            bf16x8 af[4];
#pragma unroll
            for (int mt = 0; mt < 4; ++mt)
                af[mt] = *(const bf16x8*)(K2 + kof + (unsigned)mt * (16u * KDIM) + pk);
            __builtin_amdgcn_s_setprio(1);
#pragma unroll
            for (int mt = 0; mt < 4; ++mt)
#pragma unroll
                for (int nt = 0; nt < 4; ++nt)
                    acc[mt][nt] = __builtin_amdgcn_mfma_f32_16x16x32_bf16(
                        af[mt], bq[nt], acc[mt][nt], 0, 0, 0);
            __builtin_amdgcn_s_setprio(0);
        }
    }

    // ---- in-register top-6: 16 keys/thread per nt-list --------------------
    float tvl[4][6]; int til[4][6];
#pragma unroll
    for (int n = 0; n < 4; ++n)
#pragma unroll
        for (int i = 0; i < 6; ++i) { tvl[n][i] = -INFINITY; til[n][i] = 0x7fffffff; }

#pragma unroll
    for (int nt = 0; nt < 4; ++nt) {
#pragma unroll
        for (int mt = 0; mt < 4; ++mt) {
            const f32x4 a = acc[mt][nt];
            const float m4 = fmaxf(fmaxf(a.x, a.y), fmaxf(a.z, a.w));
            if (m4 > tvl[nt][5]) {
                const int kk = kbase + wkh * 64 + mt * 16 + l4 * 4;
                ins6(a.x, kk + 0, tvl[nt], til[nt]);
                ins6(a.y, kk + 1, tvl[nt], til[nt]);
                ins6(a.z, kk + 2, tvl[nt], til[nt]);
                ins6(a.w, kk + 3, tvl[nt], til[nt]);
            }
        }
    }

    // ---- block merge: 8 slots/query (wkh,l4), 64 queries per pass ---------
    const int slot = wkh * 4 + l4;       // 0..7  (l4 lists are DISJOINT keys!)
#pragma unroll 1
    for (int h = 0; h < 2; ++h) {
        if (wqh == h) {                  // waves owning queries h*64..h*64+63
#pragma unroll
            for (int nt = 0; nt < 4; ++nt) {
                const int ql = nt * 16 + l15;            // 0..63
                float2* dst = mbuf + (size_t)ql * MPS + slot * 6;
#pragma unroll
                for (int e = 0; e < 6; ++e)
                    dst[e] = make_float2(tvl[nt][e], __int_as_float(til[nt][e]));
            }
        }
        __syncthreads();
        if (tid < 64) {                  // one thread per query merges 8 lists
            float tv[6]; int ti[6];
#pragma unroll
            for (int i = 0; i < 6; ++i) { tv[i] = -INFINITY; ti[i] = 0x7fffffff; }
            const float2* src = mbuf + (size_t)tid * MPS;
            for (int e = 0; e < 48; ++e) {
                float2 p = src[e];
                if (p.x < tv[5]) continue;
                insert6(p.x, __float_as_int(p.y), tv, ti);
            }
            size_t off = ((size_t)(qbase + h * 64 + tid) * NKB + kbi) * TOPK;
#pragma unroll
            for (int i = 0; i < 6; ++i)
                partials[off + i] = make_float2(tv[i], __int_as_float(ti[i]));
        }
        __syncthreads();
    }
}

// --- 3) parallel merge + fused finalize (device-scope handoff) --------------
__global__ __launch_bounds__(256) void merge_kernel(
        const float2* __restrict__ partials,
        const int* __restrict__ query_ids, const int* __restrict__ key_ids,
        int* __restrict__ counter, int* __restrict__ done,
        float* __restrict__ out) {
    __shared__ float2 lbuf[32][49];      // [row-in-block][8 parts * 6, pad 49]
    __shared__ int sc[32];
    const int tid  = threadIdx.x;
    const int rloc = tid >> 3;           // 0..31
    const int part = tid & 7;            // 0..7
    const int row  = blockIdx.x * 32 + rloc;

    // stage 1: each thread merges 8 of the 64 lists (48 entries, coalesced)
    float tv[6]; int ti[6];
#pragma unroll
    for (int i = 0; i < 6; ++i) { tv[i] = -INFINITY; ti[i] = 0x7fffffff; }
    const float2* src = partials + ((size_t)row * NKB + part * 8) * TOPK;
#pragma unroll
    for (int e = 0; e < 48; ++e) {
        float2 p = src[e];
        if (p.x < tv[5]) continue;
        insert6(p.x, __float_as_int(p.y), tv, ti);
    }
#pragma unroll
    for (int i = 0; i < 6; ++i)
        lbuf[rloc][part * 6 + i] = make_float2(tv[i], __int_as_float(ti[i]));
    __syncthreads();

    // stage 2: one thread per row merges the 8 partial lists + counts
    if (part == 0) {
        float tv2[6]; int ti2[6];
#pragma unroll
        for (int i = 0; i < 6; ++i) { tv2[i] = -INFINITY; ti2[i] = 0x7fffffff; }
#pragma unroll
        for (int e = 0; e < 48; ++e) {
            float2 p = lbuf[rloc][e];
            if (p.x < tv2[5]) continue;
            insert6(p.x, __float_as_int(p.y), tv2, ti2);
        }
        const int qid = query_ids[row];
        int cnt = 0;
#pragma unroll
        for (int r = 1; r < TOPK; ++r)
            cnt += (key_ids[ti2[r]] == qid) ? 1 : 0;
        sc[rloc] = cnt;
    }
    __syncthreads();
    if (tid == 0) {
        int c = 0;
#pragma unroll
        for (int i = 0; i < 32; ++i) c += sc[i];
        atomicAdd(counter, c);
        __threadfence();                 // counter-add visible before done-add
        int prev = atomicAdd(done, 1);
        if (prev == gridDim.x - 1) {     // last block finalizes
            int total = atomicAdd(counter, 0);   // coherent read
            out[0] = (float)total / (float)(NROWS * KSEL);
        }
    }
}

extern "C" void kernel_launch(void* const* d_in, const int* in_sizes, int n_in,
                              void* d_out, int out_size, void* d_ws, size_t ws_size,
                              hipStream_t stream) {
    (void)in_sizes; (void)n_in; (void)out_size; (void)ws_size;
    const int*   query_ids = (const int*)d_in[0];
    const int*   key_ids   = (const int*)d_in[1];
    const float* q         = (const float*)d_in[2];
    const float* kb        = (const float*)d_in[3];

    char* ws = (char*)d_ws;
    const size_t MB16 = (size_t)NROWS * KDIM * sizeof(unsigned short);  // 16 MB
    int*            counter  = (int*)ws;          // [0]=matches, [1]=done
    unsigned short* Q2       = (unsigned short*)(ws + 256);
    unsigned short* K2       = (unsigned short*)(ws + 256 + MB16);
    float2*         partials = (float2*)(ws + 256 + 2 * MB16);

    hipMemsetAsync(counter, 0, 2 * sizeof(int), stream);
    prep_kernel<<<(2 * NROWS) / 4, 256, 0, stream>>>(q, kb, Q2, K2);
    gemm_topk_kernel<<<dim3(NQB, NKB), 256, 0, stream>>>(Q2, K2, partials);
    merge_kernel<<<NROWS / 32, 256, 0, stream>>>(partials, query_ids, key_ids,
                                                 counter, counter + 1,
                                                 (float*)d_out);
}